// Round 6
// baseline (1629.771 us; speedup 1.0000x reference)
//
#include <hip/hip_runtime.h>
#include <stdint.h>

typedef unsigned int u32;
typedef unsigned long long u64;

// ---------------- marching-tets tables ----------------
__device__ __constant__ int c_TRI[16][6] = {
 {-1,-1,-1,-1,-1,-1},{1,0,2,-1,-1,-1},{4,0,3,-1,-1,-1},{1,4,2,1,3,4},
 {3,1,5,-1,-1,-1},{2,3,0,2,5,3},{1,4,0,1,5,4},{4,2,5,-1,-1,-1},
 {4,5,2,-1,-1,-1},{4,1,0,4,5,1},{3,2,0,3,5,2},{1,3,5,-1,-1,-1},
 {4,1,2,4,3,1},{3,0,4,-1,-1,-1},{2,0,1,-1,-1,-1},{-1,-1,-1,-1,-1,-1}};
__device__ __constant__ int c_NTRI[16] = {0,1,1,2,1,2,2,1,1,2,2,1,2,1,1,0};
__device__ __constant__ int c_NTET[16] = {0,1,1,3,1,3,3,3,1,3,3,3,3,3,3,1};
__device__ __constant__ int c_TET[16][12] = {
 {-1,-1,-1,-1,-1,-1,-1,-1,-1,-1,-1,-1},{0,4,5,6,-1,-1,-1,-1,-1,-1,-1,-1},
 {1,4,8,7,-1,-1,-1,-1,-1,-1,-1,-1},{7,1,8,6,5,1,7,6,5,0,1,6},
 {2,5,7,9,-1,-1,-1,-1,-1,-1,-1,-1},{4,0,6,7,9,0,7,6,7,0,9,2},
 {4,1,9,8,5,1,9,4,5,1,2,9},{6,0,1,2,8,6,1,2,9,6,8,2},
 {3,6,9,8,-1,-1,-1,-1,-1,-1,-1,-1},{5,0,4,8,5,0,8,3,5,8,9,3},
 {1,4,7,3,4,7,6,3,9,6,7,3},{0,1,5,3,5,1,9,3,5,1,7,9},
 {5,2,3,7,3,6,5,8,3,5,7,8},{0,4,7,8,0,3,8,7,0,3,7,2},
 {4,1,2,3,4,3,2,5,4,3,5,6},{0,1,2,3,-1,-1,-1,-1,-1,-1,-1,-1}};
__device__ __constant__ int c_EV[12] = {0,1,0,2,0,3,1,2,1,3,2,3};

// header: 0:V 1:E 3:Ecross 4:Nf1 5:Nf2 6:Nt1 7:Nt3 8:Ninner 9:NU 10:R
#define GSLOOP(i,n) for (long long i = (long long)blockIdx.x*blockDim.x + threadIdx.x; \
                         i < (long long)(n); i += (long long)gridDim.x*blockDim.x)

// ---------------- generic exclusive scan (u32, in place) ----------------
__global__ __launch_bounds__(256) void k_scan1(u32* data, u32* partials,
                                               const u32* hdr, int nslot, u32 nmax) {
  __shared__ u32 lds[2048];
  __shared__ u32 tsum[256];
  u32 n = (nslot >= 0) ? hdr[nslot] : nmax;
  u32 base = blockIdx.x * 2048u;
  for (int k = threadIdx.x; k < 2048; k += 256) {
    u32 i = base + (u32)k;
    lds[k] = (i < n) ? data[i] : 0u;
  }
  __syncthreads();
  u32 o = threadIdx.x * 8u;
  u32 run = 0; u32 loc[8];
  #pragma unroll
  for (int j = 0; j < 8; j++) { loc[j] = run; run += lds[o + j]; }
  tsum[threadIdx.x] = run;
  __syncthreads();
  for (int off = 1; off < 256; off <<= 1) {
    u32 v = tsum[threadIdx.x];
    u32 add = (threadIdx.x >= (u32)off) ? tsum[threadIdx.x - off] : 0u;
    __syncthreads();
    tsum[threadIdx.x] = v + add;
    __syncthreads();
  }
  u32 texc = (threadIdx.x == 0) ? 0u : tsum[threadIdx.x - 1];
  #pragma unroll
  for (int j = 0; j < 8; j++) {
    u32 i = base + o + (u32)j;
    if (i < n) data[i] = texc + loc[j];
  }
  if (threadIdx.x == 0) partials[blockIdx.x] = tsum[255];
}

__global__ __launch_bounds__(1024) void k_scan2(u32* partials, const u32* hdr, int nslot,
                                                u32 nmax, u32* hdrw, int tslot) {
  __shared__ u32 lds[8192];
  __shared__ u32 tsum[1024];
  u32 n = (nslot >= 0) ? hdr[nslot] : nmax;
  u32 nb = (n + 2047u) / 2048u;
  for (int k = threadIdx.x; k < 8192; k += 1024) lds[k] = ((u32)k < nb) ? partials[k] : 0u;
  __syncthreads();
  u32 o = threadIdx.x * 8u;
  u32 run = 0; u32 loc[8];
  #pragma unroll
  for (int j = 0; j < 8; j++) { loc[j] = run; run += lds[o + j]; }
  tsum[threadIdx.x] = run;
  __syncthreads();
  for (int off = 1; off < 1024; off <<= 1) {
    u32 v = tsum[threadIdx.x];
    u32 add = (threadIdx.x >= (u32)off) ? tsum[threadIdx.x - off] : 0u;
    __syncthreads();
    tsum[threadIdx.x] = v + add;
    __syncthreads();
  }
  u32 texc = (threadIdx.x == 0) ? 0u : tsum[threadIdx.x - 1];
  #pragma unroll
  for (int j = 0; j < 8; j++) { u32 k = o + (u32)j; if (k < nb) partials[k] = texc + loc[j]; }
  if (threadIdx.x == 0 && tslot >= 0) hdrw[tslot] = tsum[1023];
}

__global__ __launch_bounds__(256) void k_scan3(u32* data, const u32* partials,
                                               const u32* hdr, int nslot, u32 nmax) {
  u32 n = (nslot >= 0) ? hdr[nslot] : nmax;
  u32 base = blockIdx.x * 2048u;
  if (base >= n || blockIdx.x == 0) return;
  u32 add = partials[blockIdx.x];
  if (add == 0) return;
  for (int k = threadIdx.x; k < 2048; k += 256) {
    u32 i = base + (u32)k;
    if (i < n) data[i] += add;
  }
}

// ---------------- pipeline kernels ----------------
__global__ void k_zero32(u32* p, long long n) { GSLOOP(i, n) p[i] = 0u; }
__global__ void k_zero_hdr(u32* p, const u32* hdr, int slot, u32 extra) {
  long long n = (long long)hdr[slot] + extra;
  GSLOOP(i, n) p[i] = 0u;
}
__global__ void k_copy32(const u32* s, u32* d, long long n) { GSLOOP(i, n) d[i] = s[i]; }
__global__ void k_setr(u32* hdr, int N) { hdr[10] = (u32)N + hdr[3]; }

__global__ void k_occ(const float* sdf, const float* th, unsigned char* occ, int N) {
  float t = th[0];
  GSLOOP(i, N) { float s = sdf[i]; occ[i] = (s > 0.f && s <= t) ? 1 : 0; }
}

__global__ void k_ti(const int* tet, const unsigned char* occ, unsigned char* ti,
                     u32* S1, long long F) {
  GSLOOP(f, F) {
    int v0 = tet[4*f], v1 = tet[4*f+1], v2 = tet[4*f+2], v3 = tet[4*f+3];
    int b = (int)occ[v0] | ((int)occ[v1] << 1) | ((int)occ[v2] << 2) | ((int)occ[v3] << 3);
    ti[f] = (unsigned char)b;
    S1[f] = (b != 0 && b != 15) ? 1u : 0u;
  }
}

__global__ void k_compact_valid(const u32* S1, const unsigned char* ti, u32* vidx, long long F) {
  GSLOOP(f, F) { int b = ti[f]; if (b != 0 && b != 15) vidx[S1[f]] = (u32)f; }
}

// one pass: emit packed edge records sequentially + histogram of mn
__global__ void k_edges(const int* tet, const u32* vidx, const u32* hdr,
                        u32* hist, u64* erec, int SB, int OB) {
  u32 V = hdr[0];
  GSLOOP(t, V) {
    long long f = vidx[t];
    int v[4] = { tet[4*f], tet[4*f+1], tet[4*f+2], tet[4*f+3] };
    #pragma unroll
    for (int e = 0; e < 6; e++) {
      int a = v[c_EV[2*e]], b = v[c_EV[2*e+1]];
      int mn = a < b ? a : b, mx = a < b ? b : a;
      atomicAdd(&hist[mn], 1u);
      u64 key = (((u64)(u32)mn << (SB + OB)) | ((u64)(u32)mx << OB)) | (u64)(6ull * t + e);
      __builtin_nontemporal_store(key, &erec[6ll * t + e]);
    }
  }
}

// 33 equal-mass boundaries over the mn histogram (off = scanned hist)
__global__ void k_bnd32(const u32* off, const u32* hdr, u32* bnd, int N) {
  int g = threadIdx.x;
  if (g > 32) return;
  if (g == 32) { bnd[32] = (u32)N; return; }
  u64 target = ((u64)hdr[1] * (u64)g) / 32ull;
  u32 lo = 0, hi = (u32)N;
  while (lo < hi) { u32 m = (lo + hi) >> 1; if ((u64)off[m] < target) lo = m + 1; else hi = m; }
  bnd[g] = lo;
}

// round r: XCD g handles mn-slice r*8+g (1/32 mass ~ 1.8MB L2-resident window)
__global__ void k_scatter32(const u64* erec, const u32* bnd, const u32* hdr,
                            u32* cursor, u64* keys, int SB, int OB, int round) {
  int g = blockIdx.x & 7;
  int sidx = round * 8 + g;
  u32 lo = bnd[sidx], hi = bnd[sidx + 1];
  u32 E = hdr[1];
  for (long long i = (long long)(blockIdx.x >> 3) * blockDim.x + threadIdx.x; i < (long long)E;
       i += (long long)(gridDim.x >> 3) * blockDim.x) {
    u64 k = __builtin_nontemporal_load(&erec[i]);
    u32 mn = (u32)(k >> (SB + OB));
    if (mn >= lo && mn < hi) {
      u32 p = atomicAdd(&cursor[mn], 1u);
      keys[p] = k;
    }
  }
}

template<int KMAX>
__device__ __forceinline__ void bitonic_lane(u64& val, int lane) {
  #pragma unroll
  for (int k = 2; k <= KMAX; k <<= 1) {
    #pragma unroll
    for (int j = k >> 1; j > 0; j >>= 1) {
      u64 other = __shfl_xor(val, j, 64);
      bool keepmin = ((lane & k) == 0) == ((lane & j) == 0);
      bool smaller = val < other;
      val = (keepmin == smaller) ? val : other;
    }
  }
}

// lrv packing: bit31 = cf, bit30 = unique-flag, low30 = local crossing rank (strictly-before count)
__global__ __launch_bounds__(256) void k_bsort(const u32* off, u64* keys, u32* lrv,
                                               u32* bc, const unsigned char* occm, int N,
                                               int SB, int OB) {
  int lane = threadIdx.x & 63;
  u64 smask = ((u64)1 << SB) - 1;
  u64 ltm = (lane == 0) ? 0ull : (~0ull >> (64 - lane));
  long long wid = ((long long)blockIdx.x * blockDim.x + threadIdx.x) >> 6;
  long long nw  = ((long long)gridDim.x * blockDim.x) >> 6;
  for (long long v = wid; v < N; v += nw) {
    u32 s = off[v], e = off[v + 1];
    u32 cnt = e - s;
    if (cnt == 0) { if (lane == 0) bc[v] = 0u; continue; }
    int ov = (int)occm[v];
    if (cnt == 1) {
      if (lane == 0) {
        u32 mx = (u32)((keys[s] >> OB) & smask);
        u32 cf = ((ov + (int)occm[mx]) == 1) ? 1u : 0u;
        lrv[s] = (cf << 31) | (1u << 30);
        bc[v] = cf;
      }
      continue;
    }
    if (cnt <= 64) {
      u64 val = (lane < (int)cnt) ? keys[s + lane] : ~0ull;
      if      (cnt <= 2)  bitonic_lane<2>(val, lane);
      else if (cnt <= 4)  bitonic_lane<4>(val, lane);
      else if (cnt <= 8)  bitonic_lane<8>(val, lane);
      else if (cnt <= 16) bitonic_lane<16>(val, lane);
      else if (cnt <= 32) bitonic_lane<32>(val, lane);
      else                bitonic_lane<64>(val, lane);
      u64 prev = __shfl_up(val, 1, 64);
      bool inb = lane < (int)cnt;
      bool flag = inb && (lane == 0 || (val >> OB) != (prev >> OB));
      u32 mx = (u32)((val >> OB) & smask);
      bool cf = inb && ((ov + (int)occm[mx]) == 1);
      u64 m = __ballot(flag && cf);
      u32 lr = (u32)__popcll(m & ltm);
      if (inb) {
        keys[s + lane] = val;
        lrv[s + lane] = (cf ? 0x80000000u : 0u) | (flag ? 0x40000000u : 0u) | lr;
      }
      if (lane == 0) bc[v] = (u32)__popcll(m);
    } else if (cnt <= 256) {
      u64 vals[4];
      #pragma unroll
      for (int r = 0; r < 4; r++) {
        int idx = r * 64 + lane;
        vals[r] = (idx < (int)cnt) ? keys[s + idx] : ~0ull;
      }
      #pragma unroll
      for (int k = 2; k <= 256; k <<= 1) {
        #pragma unroll
        for (int j = 128; j > 0; j >>= 1) {
          if (j >= k) continue;
          if (j >= 64) {
            int rj = j >> 6;
            #pragma unroll
            for (int r = 0; r < 4; r++) {
              int pr = r ^ rj;
              if (pr > r) {
                int i0 = r * 64 + lane;
                bool keepmin = ((i0 & k) == 0);
                u64 a = vals[r], b = vals[pr];
                u64 mn = a < b ? a : b, mx = a < b ? b : a;
                vals[r]  = keepmin ? mn : mx;
                vals[pr] = keepmin ? mx : mn;
              }
            }
          } else {
            #pragma unroll
            for (int r = 0; r < 4; r++) {
              int i0 = r * 64 + lane;
              u64 other = __shfl_xor(vals[r], j, 64);
              bool keepmin = ((i0 & k) == 0) == ((i0 & j) == 0);
              bool smaller = vals[r] < other;
              vals[r] = (keepmin == smaller) ? vals[r] : other;
            }
          }
        }
      }
      bool flags[4], cfs[4]; u64 masks[4];
      #pragma unroll
      for (int r = 0; r < 4; r++) {
        u64 pv = __shfl_up(vals[r], 1, 64);
        u64 lastprev = (r > 0) ? __shfl(vals[r - 1], 63, 64) : 0ull;
        int idx = r * 64 + lane;
        u64 prev = (lane == 0) ? lastprev : pv;
        bool inb = idx < (int)cnt;
        flags[r] = inb && (idx == 0 || (vals[r] >> OB) != (prev >> OB));
        u32 mx = (u32)((vals[r] >> OB) & smask);
        cfs[r] = inb && ((ov + (int)occm[mx]) == 1);
        masks[r] = __ballot(flags[r] && cfs[r]);
      }
      u32 base = 0;
      #pragma unroll
      for (int r = 0; r < 4; r++) {
        u32 lr = base + (u32)__popcll(masks[r] & ltm);
        int idx = r * 64 + lane;
        if (idx < (int)cnt) {
          keys[s + idx] = vals[r];
          lrv[s + idx] = (cfs[r] ? 0x80000000u : 0u) | (flags[r] ? 0x40000000u : 0u) | lr;
        }
        base += (u32)__popcll(masks[r]);
      }
      if (lane == 0) bc[v] = base;
    } else if (lane == 0) {
      for (u32 i = s + 1; i < e; i++) {
        u64 kk = keys[i]; u32 j = i;
        while (j > s && keys[j - 1] > kk) { keys[j] = keys[j - 1]; j--; }
        keys[j] = kk;
      }
      u32 lr = 0;
      for (u32 j = s; j < e; j++) {
        bool flag = (j == s) || ((keys[j] >> OB) != (keys[j - 1] >> OB));
        u32 mx = (u32)((keys[j] >> OB) & smask);
        bool cf = ((ov + (int)occm[mx]) == 1);
        lrv[j] = (cf ? 0x80000000u : 0u) | (flag ? 0x40000000u : 0u) | lr;
        if (flag && cf) lr++;
      }
      bc[v] = lr;
    }
  }
}

// flat pass over sorted positions: write interp verts (sequential in rank) + (oix, mv) streams
__global__ void k_ie_interp(const u64* keys, const u32* lrv, const u32* bc0,
                            const float* pos, const float* sdf, const float* th,
                            u32* oix, int* mv, float* out, const u32* hdr, int SB, int OB) {
  u32 E = hdr[1];
  float t = th[0];
  u64 omask = ((u64)1 << OB) - 1;
  u64 smask = ((u64)1 << SB) - 1;
  GSLOOP(i, E) {
    u64 k = __builtin_nontemporal_load(&keys[i]);
    u32 l = __builtin_nontemporal_load(&lrv[i]);
    u32 oidx = (u32)(k & omask);
    bool cf = (l >> 31) & 1, flag = (l >> 30) & 1;
    u32 lr = l & 0x3fffffffu;
    int mapv = -1;
    if (cf) {
      u32 mn = (u32)(k >> (SB + OB));
      u32 rank = bc0[mn] + lr - (flag ? 0u : 1u);
      mapv = (int)rank;
      if (flag) {
        int a = (int)mn, b = (int)(u32)((k >> OB) & smask);
        float s0 = sdf[a], s1 = sdf[b];
        if (s0 > 0.f && s1 > 0.f) { s0 = __fsub_rn(s0, t); s1 = __fsub_rn(s1, t); }
        float denom = __fadd_rn(s0, -s1);
        float w0 = __fdiv_rn(-s1, denom);
        float w1 = __fdiv_rn(s0, denom);
        long long base = 3ll * rank;
        #pragma unroll
        for (int kk = 0; kk < 3; kk++)
          out[base + kk] = __fadd_rn(__fmul_rn(pos[3ll*a + kk], w0), __fmul_rn(pos[3ll*b + kk], w1));
      }
    }
    __builtin_nontemporal_store(oidx, &oix[i]);
    __builtin_nontemporal_store(mapv, &mv[i]);
  }
}

// 8-sliced scatter of mapvals back to occurrence order
__global__ void k_fin(const u32* oix, const int* mv, int* idx_map, const u32* hdr) {
  u32 E = hdr[1];
  int g = blockIdx.x & 7;
  for (long long i = (long long)(blockIdx.x >> 3) * blockDim.x + threadIdx.x; i < (long long)E;
       i += (long long)(gridDim.x >> 3) * blockDim.x) {
    u32 o = __builtin_nontemporal_load(&oix[i]);
    int m = __builtin_nontemporal_load(&mv[i]);
    u32 slice = (u32)(((u64)o * 8ull) / (u64)E);
    if (slice == (u32)g) idx_map[o] = m;
  }
}

// all five compaction predicates in one ti pass
__global__ void k_predall(const unsigned char* ti, u32* Sf1, u32* Sf2,
                          u32* St1, u32* St3, u32* Si, long long F) {
  GSLOOP(f, F) {
    int b = ti[f]; bool valid = (b != 0 && b != 15);
    int nt = c_NTRI[b]; int ntt = c_NTET[b];
    Sf1[f] = (valid && nt == 1) ? 1u : 0u;
    Sf2[f] = (valid && nt == 2) ? 1u : 0u;
    St1[f] = (valid && ntt == 1) ? 1u : 0u;
    St3[f] = (valid && ntt == 3) ? 1u : 0u;
    Si[f]  = (b == 15) ? 1u : 0u;
  }
}

// fused faces + surface-tet emission
__global__ void k_emit_ft(const int* tet, const u32* vidx, const unsigned char* ti,
                          const int* idx_map, const u32* Sf1, const u32* Sf2,
                          const u32* St1, const u32* St3, float* out, int* at,
                          const u32* hdr, int N) {
  u32 V = hdr[0];
  unsigned long long fo = 3ull * hdr[3];
  u32 Nf1 = hdr[4], Nt1 = hdr[6];
  GSLOOP(t, V) {
    u32 f = vidx[t]; int b = ti[f];
    int im[6];
    #pragma unroll
    for (int j = 0; j < 6; j++) im[j] = idx_map[6*t + j];
    int nt = c_NTRI[b];
    if (nt == 1) {
      unsigned long long base = fo + 3ull * Sf1[f];
      for (int k = 0; k < 3; k++) out[base + k] = (float)im[c_TRI[b][k]];
    } else {
      unsigned long long base = fo + 3ull * Nf1 + 6ull * Sf2[f];
      for (int k = 0; k < 6; k++) out[base + k] = (float)im[c_TRI[b][k]];
    }
    int tv[10];
    for (int k = 0; k < 4; k++) tv[k] = tet[4ll*f + k];
    for (int j = 0; j < 6; j++) tv[4 + j] = im[j] + N;
    int ntt = c_NTET[b];
    if (ntt == 1) {
      long long base = 4ll * St1[f];
      for (int k = 0; k < 4; k++) at[base + k] = tv[c_TET[b][k]];
    } else {
      long long base = 4ll * Nt1 + 12ll * St3[f];
      for (int k = 0; k < 12; k++) at[base + k] = tv[c_TET[b][k]];
    }
  }
}

__global__ void k_tets_inner(const int* tet, const unsigned char* ti, const u32* Si,
                             int* at, const u32* hdr, long long F) {
  long long base0 = 4ll * hdr[6] + 12ll * hdr[7];
  GSLOOP(f, F) {
    if (ti[f] == 15) {
      long long base = base0 + 4ll * Si[f];
      for (int k = 0; k < 4; k++) at[base + k] = tet[4*f + k];
    }
  }
}

__global__ void k_mark(const int* at, u32* Big, const u32* hdr) {
  long long NA = 4ll * hdr[6] + 12ll * hdr[7] + 4ll * hdr[8];
  GSLOOP(i, NA) Big[at[i]] = 1u;
}

__global__ void k_vtm(const u32* Big, const float* pos, float* out, const u32* hdr, int N) {
  u32 R = hdr[10], NU = hdr[9];
  unsigned long long vtm = 3ull * hdr[3] + 3ull * (hdr[4] + 2u * hdr[5]);
  GSLOOP(v, R) {
    u32 r = Big[v];
    u32 nx = (v + 1 < (long long)R) ? Big[v + 1] : NU;
    if (nx > r) {
      unsigned long long base = vtm + 3ull * r;
      if (v < N) { for (int k = 0; k < 3; k++) out[base + k] = pos[3*v + k]; }
      else { long long src = 3ll * (v - N); for (int k = 0; k < 3; k++) out[base + k] = out[src + k]; }
    }
  }
}

__global__ void k_tets_out(const int* at, const u32* Big, float* out, const u32* hdr) {
  long long NA = 4ll * hdr[6] + 12ll * hdr[7] + 4ll * hdr[8];
  unsigned long long toff = 3ull * hdr[3] + 3ull * (hdr[4] + 2u * hdr[5]) + 3ull * hdr[9];
  GSLOOP(i, NA) out[toff + i] = (float)Big[at[i]];
}

// ---------------- host ----------------
extern "C" void kernel_launch(void* const* d_in, const int* in_sizes, int n_in,
                              void* d_out, int out_size, void* d_ws, size_t ws_size,
                              hipStream_t stream) {
  const float* pos = (const float*)d_in[0];
  const float* sdf = (const float*)d_in[1];
  const int*   tet = (const int*)d_in[2];
  const float* th  = (const float*)d_in[3];
  float* out = (float*)d_out;

  const int N = in_sizes[1];
  const long long F = (long long)in_sizes[2] / 4;
  const long long MAXE = 6 * F;
  const long long RMAX = (long long)N + MAXE;
  (void)n_in; (void)out_size; (void)ws_size;

  int SB = 1; while ((1ll << SB) < (long long)N) SB++;
  int OB = 1; while ((1ll << OB) < MAXE) OB++;

  char* w = (char*)d_ws;
  size_t off = 0;
  auto alloc = [&](size_t b) -> char* {
    char* p = w + off; off = (off + b + 255) & ~(size_t)255; return p;
  };
  u32* hdr            = (u32*)alloc(64 * 4);
  u32* bnd            = (u32*)alloc(64 * 4);
  unsigned char* occ  = (unsigned char*)alloc((size_t)N);
  unsigned char* tiA  = (unsigned char*)alloc((size_t)F);
  u32* S1             = (u32*)alloc(4 * (size_t)F);
  u32* S2             = (u32*)alloc(4 * (size_t)F);
  u32* S3             = (u32*)alloc(4 * (size_t)F);
  u32* S4             = (u32*)alloc(4 * (size_t)F);
  u32* S5             = (u32*)alloc(4 * (size_t)F);
  u32* vidx           = (u32*)alloc(4 * (size_t)F);
  u32* hist           = (u32*)alloc(4 * ((size_t)N + 2));
  u32* cursor         = (u32*)alloc(4 * ((size_t)N + 2));
  u32* bc             = (u32*)alloc(4 * ((size_t)N + 2));
  // erec region (8*MAXE); reused as Big (4*(RMAX+2) <= 8*MAXE) after scatter rounds
  char* erec_mem      = alloc(8 * (size_t)MAXE);
  u64* erec = (u64*)erec_mem; u32* Big = (u32*)erec_mem;
  // keys region (8*MAXE); reused as at (4*12F) after k_ie_interp
  char* keys_mem      = alloc(8 * (size_t)MAXE);
  u64* keys = (u64*)keys_mem; int* at = (int*)keys_mem;
  u32* lrv            = (u32*)alloc(4 * (size_t)MAXE);
  u32* oix            = (u32*)alloc(4 * (size_t)MAXE);
  int* mv             = (int*)alloc(4 * (size_t)MAXE);
  int* idx_map        = (int*)alloc(4 * (size_t)MAXE);
  u32* partials       = (u32*)alloc(4 * 8192);

  const int GRID = 4096, BLK = 256;
  auto scan = [&](u32* data, int nslot, u32 nmax, int tslot) {
    int nb = (int)((nmax + 2047u) / 2048u);
    k_scan1<<<nb, 256, 0, stream>>>(data, partials, hdr, nslot, nmax);
    k_scan2<<<1, 1024, 0, stream>>>(partials, hdr, nslot, nmax, hdr, tslot);
    k_scan3<<<nb, 256, 0, stream>>>(data, partials, hdr, nslot, nmax);
  };

  k_zero32<<<1, 64, 0, stream>>>(hdr, 64);
  k_zero32<<<2048, BLK, 0, stream>>>(hist, (long long)N + 2);

  k_occ<<<GRID, BLK, 0, stream>>>(sdf, th, occ, N);
  k_ti<<<GRID, BLK, 0, stream>>>(tet, occ, tiA, S1, F);
  scan(S1, -1, (u32)F, 0);                                    // hdr[0] = V
  k_compact_valid<<<GRID, BLK, 0, stream>>>(S1, tiA, vidx, F);

  k_edges<<<GRID, BLK, 0, stream>>>(tet, vidx, hdr, hist, erec, SB, OB);
  scan(hist, -1, (u32)(N + 1), 1);                            // hdr[1] = E; hist -> off
  k_bnd32<<<1, 64, 0, stream>>>(hist, hdr, bnd, N);
  k_copy32<<<GRID, BLK, 0, stream>>>(hist, cursor, (long long)N + 2);
  for (int r = 0; r < 4; r++)
    k_scatter32<<<GRID, BLK, 0, stream>>>(erec, bnd, hdr, cursor, keys, SB, OB, r);
  k_bsort<<<GRID, BLK, 0, stream>>>(hist, keys, lrv, bc, occ, N, SB, OB);

  scan(bc, -1, (u32)N, 3);                                    // hdr[3] = Ecross; bc -> bc0
  k_setr<<<1, 1, 0, stream>>>(hdr, N);                        // hdr[10] = R
  k_ie_interp<<<GRID, BLK, 0, stream>>>(keys, lrv, bc, pos, sdf, th, oix, mv, out, hdr, SB, OB);
  k_fin<<<GRID, BLK, 0, stream>>>(oix, mv, idx_map, hdr);

  k_predall<<<GRID, BLK, 0, stream>>>(tiA, S1, S2, S3, S4, S5, F);
  scan(S1, -1, (u32)F, 4);                                    // hdr[4] = Nf1
  scan(S2, -1, (u32)F, 5);                                    // hdr[5] = Nf2
  scan(S3, -1, (u32)F, 6);                                    // hdr[6] = Nt1
  scan(S4, -1, (u32)F, 7);                                    // hdr[7] = Nt3
  scan(S5, -1, (u32)F, 8);                                    // hdr[8] = Ninner
  k_emit_ft<<<GRID, BLK, 0, stream>>>(tet, vidx, tiA, idx_map, S1, S2, S3, S4, out, at, hdr, N);
  k_tets_inner<<<GRID, BLK, 0, stream>>>(tet, tiA, S5, at, hdr, F);

  k_zero_hdr<<<GRID, BLK, 0, stream>>>(Big, hdr, 10, 2u);
  k_mark<<<GRID, BLK, 0, stream>>>(at, Big, hdr);
  scan(Big, 10, (u32)RMAX, 9);                                // hdr[9] = NU
  k_vtm<<<GRID, BLK, 0, stream>>>(Big, pos, out, hdr, N);
  k_tets_out<<<GRID, BLK, 0, stream>>>(at, Big, out, hdr);
}